// Round 20
// baseline (281.115 us; speedup 1.0000x reference)
//
#include <hip/hip_runtime.h>
#include <hip/hip_bf16.h>
#include <math.h>

#define B_   16
#define S_   4096
#define DIN  1024
#define V_   512
#define FOUT 120

typedef __attribute__((ext_vector_type(8))) short bf16x8;
typedef __attribute__((ext_vector_type(16))) float f32x16;

#define AS1 __attribute__((address_space(1)))
#define AS3 __attribute__((address_space(3)))

__device__ const float CSCALE = 0.1f / (64.0f * 4096.0f);
__device__ const float EPSF = 1e-5f;

__device__ inline void gl2lds16(const void* g, void* l) {
  __builtin_amdgcn_global_load_lds((const AS1 unsigned int*)g,
                                   (AS3 unsigned int*)l, 16, 0, 0);
}

// fp32 -> bf16 RNE
__device__ inline unsigned short f2b(float f) {
  unsigned u = __builtin_bit_cast(unsigned, f);
  unsigned r = (u + 0x7FFFu + ((u >> 16) & 1u)) >> 16;
  return (unsigned short)r;
}

__device__ inline bf16x8 pack8(float4 a, float4 b) {
  bf16x8 r;
  r[0] = (short)f2b(a.x); r[1] = (short)f2b(a.y);
  r[2] = (short)f2b(a.z); r[3] = (short)f2b(a.w);
  r[4] = (short)f2b(b.x); r[5] = (short)f2b(b.y);
  r[6] = (short)f2b(b.z); r[7] = (short)f2b(b.w);
  return r;
}

// Fused pre-pass. Blocks 0..767: convert W to frag-major Wt for 32x32x16 frags:
// chunk e = ((ct*32 + k)*24 + f)*64 + l ; f = kh*12 + nf*3 + g (kh 0..1, nf 0..3, g 0..2)
// lane l: channel ct*128 + nf*32 + (l&31), k-elem k*32 + kh*16 + (l>>5)*8 .. +8
// Blocks 768..2815: x -> Xb bf16 (r6-r17-verified). Last block: zero outacc.
template <bool DOX>
__global__ __launch_bounds__(256) void msr_conv(
    const float* __restrict__ Wq, const float* __restrict__ Wk,
    const float* __restrict__ Wv, const float* __restrict__ x,
    unsigned short* __restrict__ Wt, unsigned short* __restrict__ Xb,
    float* __restrict__ outacc) {
  const int bid = blockIdx.x;
  if (bid < 768) {
    int e = bid * 256 + threadIdx.x;
    int l = e & 63;
    int f = (e >> 6) % 24;
    int ck = (e >> 6) / 24;
    int k = ck & 31;
    int ct = ck >> 5;
    int kh = f / 12;
    int nf = (f % 12) / 3;
    int g = f % 3;
    const float* W = (g == 0) ? Wq : (g == 1) ? Wk : Wv;
    int ch = ct * 128 + nf * 32 + (l & 31);
    const float* src = W + (size_t)ch * DIN + k * 32 + kh * 16 + (l >> 5) * 8;
    float4 a = *(const float4*)src;
    float4 b = *(const float4*)(src + 4);
    *(bf16x8*)(Wt + (size_t)e * 8) = pack8(a, b);
  } else if (DOX && bid < 2816) {
    const size_t stride = 2048ull * 256;
    for (size_t i = (size_t)(bid - 768) * 256 + threadIdx.x; i < 8388608ull; i += stride) {
      const float* src = x + i * 8;
      float4 a = *(const float4*)src;
      float4 b = *(const float4*)(src + 4);
      *(bf16x8*)(Xb + i * 8) = pack8(a, b);
    }
  } else {
    for (int i = threadIdx.x; i < B_ * V_; i += 256) outacc[i] = 0.f;
  }
}

#define WAITVM5  asm volatile("s_waitcnt vmcnt(5)" ::: "memory")
#define WAITVM3  asm volatile("s_waitcnt vmcnt(3)" ::: "memory")
#define WAITVM0  asm volatile("s_waitcnt vmcnt(0)" ::: "memory")
#define WAITLGKM asm volatile("s_waitcnt lgkmcnt(0)" ::: "memory")
#define SCHEDB   __builtin_amdgcn_sched_barrier(0)
#define BARRIER  { asm volatile("" ::: "memory"); __builtin_amdgcn_s_barrier(); asm volatile("" ::: "memory"); }

// Main — r12 sync skeleton VERBATIM; MFMA shape 16x16x32 -> 32x32x16 (+15% rate).
// BM=256 x 128ch x 3g, BK=32, 32 steps, 512 thr = 8 waves (2M x 4N).
// Wave tile 128r x 32ch x 3g: 4 m-frags (32r) x 1 n-frag (32ch) x 3 g x 2 kh
// = 24 MFMAs/step, acc[3][4] f32x16 = 192 AGPR (identical budget).
// LDS per buf: A 16 x 1KB units [(kh*8 + m)*1024] | B 24 x 1KB [(kh*12+nf*3+g)*1024].
// Same 14 ds_read_b128 + 5 gl2lds per wave-step; 3-buf, 1 barrier/step, vmcnt(5).
template <bool DIRECT>
__global__ __launch_bounds__(512, 2) void msr_main(
    const float* __restrict__ x, const unsigned short* __restrict__ Xb,
    const unsigned short* __restrict__ Wt, float* __restrict__ outacc) {
  const int bid = blockIdx.x;
  const int xcd = bid & 7;
  const int j = bid >> 3;               // 0..127 per-XCD order
  const int ct = j & 3;                 // ct fastest: same rt 4x consecutive (L2-hot x)
  const int rt = xcd * 32 + (j >> 2);   // 0..255, bijective (r12-verified)
  const int r0 = rt << 8;

  __shared__ __align__(16) unsigned char smem_[122880];  // 3 x (A 16KB | B 24KB)

  const int t = threadIdx.x;
  const int w = t >> 6, lane = t & 63;
  const int l16 = lane * 16;
  const int w3 = w * 3;
  const int ctk = ct * 32;
  const int amb = (w >> 2) * 4096;                          // A m-frag base (bytes)
  const int bread0 = 16384 + (w & 3) * 3 * 1024 + l16;      // B kh=0 frag base
  // kh=1 adds 12*1024 to B, 8*1024 to A.

  // A staging: wave w stages units {w (kh=0), 8+w (kh=1)} of its step image.
  // lane l -> row r0 + w*32 + (l&31), k-octet l>>5 (pre-swizzled source,
  // linear LDS dest base + lane*16). kh=1 source = +16 shorts.
  const unsigned short* srcA0 =
      Xb + (size_t)(r0 + w * 32 + (lane & 31)) * DIN + ((lane >> 5) << 3);
  // fallback: f32 + pack + lane-linear ds_write (same unit map)
  const float* pXf = x + (size_t)(r0 + w * 32 + (lane & 31)) * DIN + ((lane >> 5) << 3);

  f32x16 acc[3][4];
#pragma unroll
  for (int g = 0; g < 3; ++g)
#pragma unroll
    for (int m = 0; m < 4; ++m)
#pragma unroll
      for (int r = 0; r < 16; ++r) acc[g][m][r] = 0.f;

#define STAGE(KK, SB) { \
  unsigned char* _sb = smem_ + (SB) * 40960; \
  if constexpr (DIRECT) { \
    gl2lds16(srcA0 + (size_t)(KK) * 32, _sb + w * 1024); \
    gl2lds16(srcA0 + (size_t)(KK) * 32 + 16, _sb + (8 + w) * 1024); \
  } else { \
    const float* _p0 = pXf + (size_t)(KK) * 32; \
    const float* _p1 = _p0 + 16; \
    *(bf16x8*)(_sb + w * 1024 + l16) = \
        pack8(*(const float4*)_p0, *(const float4*)(_p0 + 4)); \
    *(bf16x8*)(_sb + (8 + w) * 1024 + l16) = \
        pack8(*(const float4*)_p1, *(const float4*)(_p1 + 4)); \
  } \
  _Pragma("unroll") for (int i = 0; i < 3; ++i) \
    gl2lds16(Wt + ((size_t)(ctk + (KK)) * 24 + w3 + i) * 512 + (size_t)lane * 8, \
             _sb + 16384 + (w3 + i) * 1024); }

#define COMPUTE(KB) { \
  const unsigned char* _kb = smem_ + (KB) * 40960; \
  bf16x8 _bfr[6]; \
  _Pragma("unroll") for (int kh = 0; kh < 2; ++kh) \
    _Pragma("unroll") for (int g = 0; g < 3; ++g) \
      _bfr[kh * 3 + g] = *(const bf16x8*)(_kb + bread0 + (kh * 12 + g) * 1024); \
  __builtin_amdgcn_s_setprio(1); \
  _Pragma("unroll") for (int m = 0; m < 4; ++m) { \
    bf16x8 _a0 = *(const bf16x8*)(_kb + amb + m * 1024 + l16); \
    bf16x8 _a1 = *(const bf16x8*)(_kb + 8192 + amb + m * 1024 + l16); \
    _Pragma("unroll") for (int g = 0; g < 3; ++g) \
      acc[g][m] = __builtin_amdgcn_mfma_f32_32x32x16_bf16(_a0, _bfr[g], acc[g][m], 0, 0, 0); \
    _Pragma("unroll") for (int g = 0; g < 3; ++g) \
      acc[g][m] = __builtin_amdgcn_mfma_f32_32x32x16_bf16(_a1, _bfr[3 + g], acc[g][m], 0, 0, 0); \
  } \
  __builtin_amdgcn_s_setprio(0); }

#define STEP(KB, SB, KK, DOSTAGE, VMD, VMF) { \
  if (DOSTAGE) { STAGE((KK) + 2, SB); } \
  SCHEDB; \
  COMPUTE(KB); \
  if constexpr (DIRECT) { VMD; } else { WAITLGKM; VMF; } \
  BARRIER; }

  // ---- prologue: stage steps 0,1 into bufs 0,1 ----
  STAGE(0, 0);
  STAGE(1, 1);
  if constexpr (DIRECT) { WAITVM5; } else { WAITLGKM; WAITVM3; }
  BARRIER;

  // ---- steps 0..29 ----
#pragma unroll 1
  for (int i = 0; i < 10; ++i) {
    const int k3 = i * 3;
    STEP(0, 2, k3,     1, WAITVM5, WAITVM3);
    STEP(1, 0, k3 + 1, 1, WAITVM5, WAITVM3);
    STEP(2, 1, k3 + 2, 1, WAITVM5, WAITVM3);
  }
  // ---- step 30: no stage; full drain (incl. stage(31)) ----
  STEP(0, 0, 30, 0, WAITVM0, WAITVM0);
  // ---- step 31: compute only ----
  COMPUTE(1);
#undef STEP
#undef COMPUTE
#undef STAGE

  // ---- epilogue (32x32 C/D, guide-HW-verified m74/m101):
  // col = lane&31 (channel), row = (reg&3)+8*(reg>>2)+4*(lane>>5).
  // p = (q*k)[c^1]*v[c]: col^1 = lane^1 shuffle; fold rows in-thread + xor32.
  float pd = 0.f;
#pragma unroll
  for (int m = 0; m < 4; ++m)
#pragma unroll
    for (int r = 0; r < 16; ++r) {
      float qk = acc[0][m][r] * acc[1][m][r];
      pd += __shfl_xor(qk, 1, 64) * acc[2][m][r];
    }
  pd += __shfl_xor(pd, 32, 64);

  // rows r0..r0+255 in h-block rt>>1 ; d = (ct*128 + (w&3)*32 + (lane&31)) % 64
  if (lane < 32) {
    atomicAdd(&outacc[((rt >> 1) << 6) + (w & 1) * 32 + lane], pd);
  }
}

// Finish: per-batch RMSNorm -> exact gelu -> @ Wout.T (verified r1-r19)
__global__ __launch_bounds__(256) void msr_finish(
    const float* __restrict__ outacc, const float* __restrict__ gamma,
    const float* __restrict__ Wout, float* __restrict__ y) {
  const int b = blockIdx.x;
  const int t = threadIdx.x;
  __shared__ float g[V_];
  __shared__ float wsum[4];

  float v0 = outacc[b * V_ + t] * CSCALE;
  float v1 = outacc[b * V_ + 256 + t] * CSCALE;
  float ss = v0 * v0 + v1 * v1;
#pragma unroll
  for (int o = 32; o > 0; o >>= 1) ss += __shfl_down(ss, o, 64);
  if ((t & 63) == 0) wsum[t >> 6] = ss;
  __syncthreads();
  float tot = wsum[0] + wsum[1] + wsum[2] + wsum[3];
  float rs = rsqrtf(tot * (1.0f / (float)V_) + EPSF);

  float r0v = v0 * rs * gamma[t];
  float r1v = v1 * rs * gamma[t + 256];
  g[t]       = 0.5f * r0v * (1.0f + erff(r0v * 0.70710678118654752f));
  g[t + 256] = 0.5f * r1v * (1.0f + erff(r1v * 0.70710678118654752f));
  __syncthreads();

  if (t < FOUT) {
    const float* wr = Wout + (size_t)t * V_;
    float acc = 0.f;
#pragma unroll 4
    for (int c = 0; c < V_; c += 4) {
      float4 w4 = *(const float4*)(wr + c);
      acc += g[c] * w4.x + g[c + 1] * w4.y + g[c + 2] * w4.z + g[c + 3] * w4.w;
    }
    y[b * FOUT + t] = acc;
  }
}

extern "C" void kernel_launch(void* const* d_in, const int* in_sizes, int n_in,
                              void* d_out, int out_size, void* d_ws, size_t ws_size,
                              hipStream_t stream) {
  const float* x     = (const float*)d_in[0];
  const float* Wq    = (const float*)d_in[1];
  const float* Wk    = (const float*)d_in[2];
  const float* Wv    = (const float*)d_in[3];
  const float* Wout  = (const float*)d_in[4];
  const float* gamma = (const float*)d_in[5];

  float* outacc = (float*)d_ws;                                    // 32 KB
  unsigned short* Wt = (unsigned short*)((char*)d_ws + 32768);     // 3 MB
  unsigned short* Xb = (unsigned short*)((char*)d_ws + 32768 + 3145728);  // 128 MB
  float* y = (float*)d_out;

  const size_t need = 32768ull + 3145728ull + 134217728ull;

  if (ws_size >= need) {
    msr_conv<true><<<2817, 256, 0, stream>>>(Wq, Wk, Wv, x, Wt, Xb, outacc);
    msr_main<true><<<1024, 512, 0, stream>>>(x, Xb, Wt, outacc);
  } else {
    msr_conv<false><<<769, 256, 0, stream>>>(Wq, Wk, Wv, x, Wt, Xb, outacc);
    msr_main<false><<<1024, 512, 0, stream>>>(x, Xb, Wt, outacc);
  }
  msr_finish<<<B_, 256, 0, stream>>>(outacc, gamma, Wout, y);
}